// Round 8
// baseline (186.449 us; speedup 1.0000x reference)
//
#include <hip/hip_runtime.h>
#include <math.h>

#define D_LEN 2048
#define C_CH  128
#define NB    16

typedef __attribute__((ext_vector_type(8))) short bf16x8;
typedef __attribute__((ext_vector_type(4))) float f32x4;

__device__ __forceinline__ unsigned int f2bf(float x){
    unsigned int u = __float_as_uint(x);
    return (u + 0x7fffu + ((u >> 16) & 1u)) >> 16;     // RNE
}
__device__ __forceinline__ unsigned int pack2(float a, float b){
    return f2bf(a) | (f2bf(b) << 16);
}
__device__ __forceinline__ float bfl(unsigned int u){ return __uint_as_float(u << 16); }
__device__ __forceinline__ float bfh(unsigned int u){ return __uint_as_float(u & 0xffff0000u); }

// async global->LDS, 16B per lane; LDS dest = wave-uniform base + lane*16
__device__ __forceinline__ void gl_lds16(const void* g, void* l) {
    __builtin_amdgcn_global_load_lds(
        (const __attribute__((address_space(1))) unsigned int*)g,
        (__attribute__((address_space(3))) unsigned int*)l, 16, 0, 0);
}

// ---------------------------------------------------------------------------
// Kernel A: 1x1 convs via MFMA, one conv per blockIdx.z (3x parallelism vs
// serial-in-block r7). grid (32,16,3). W frags from global (L2-hot).
// z<2 (f,g): raw conv bf16 [b][d][c] + fused BN partial stats.
// z=2 (h): conv+bh, bf16 [b][c][d] via LDS transpose.
// ---------------------------------------------------------------------------
__global__ __launch_bounds__(256) void conv3_kernel(
    const float* __restrict__ x,
    const float* __restrict__ Wf, const float* __restrict__ Wg,
    const float* __restrict__ Wh, const float* __restrict__ bh,
    short* __restrict__ ft, short* __restrict__ gt, short* __restrict__ hh,
    float* __restrict__ part)
{
    __shared__ __align__(16) char smem[34816 + 16384];
    float* xs  = (float*)smem;              // [128][68] fp32 (phase 1)
    short* fgT = (short*)smem;              // [64][128] bf16 staging (reuse)
    short* hT  = (short*)smem;              // [128][72] bf16 (h epilogue)
    short* xt  = (short*)(smem + 34816);    // [64][128] bf16 swizzled

    const int t    = threadIdx.x;
    const int lane = t & 63;
    const int w    = t >> 6;
    const int l15  = lane & 15, lg = lane >> 4;
    const int dblk = blockIdx.x * 64;
    const int b    = blockIdx.y;
    const int z    = blockIdx.z;
    const int bid  = b * 32 + blockIdx.x;   // 0..511
    const size_t xbase = (size_t)b * C_CH * D_LEN;
    const float* W = (z == 0) ? Wf : (z == 1) ? Wg : Wh;

    // phase 1: stage x tile [c=128][d=64] fp32, coalesced
    #pragma unroll
    for (int k = 0; k < 8; ++k) {
        int u = t + k * 256;
        int c = u >> 4, d4 = (u & 15) * 4;
        float4 v = *(const float4*)(x + xbase + (size_t)c * D_LEN + dblk + d4);
        *(float4*)&xs[c * 68 + d4] = v;
    }
    __syncthreads();

    // phase 2: transpose -> xt[d][c] bf16 swizzled
    {
        const int d  = t & 63;
        const int cw = t >> 6;
        #pragma unroll
        for (int k = 0; k < 4; ++k) {
            int c0 = (cw + 4 * k) * 8;
            float v[8];
            #pragma unroll
            for (int j = 0; j < 8; ++j) v[j] = xs[(c0 + j) * 68 + d];
            uint4 o;
            o.x = pack2(v[0], v[1]); o.y = pack2(v[2], v[3]);
            o.z = pack2(v[4], v[5]); o.w = pack2(v[6], v[7]);
            *(uint4*)&xt[d * 128 + (c0 ^ ((d & 7) << 3))] = o;
        }
    }
    __syncthreads();   // xt ready; xs region free

    const f32x4 fzero = {0.f, 0.f, 0.f, 0.f};

    // W fragments straight from global fp32, pack to bf16
    bf16x8 af[2][4];
    #pragma unroll
    for (int ot = 0; ot < 2; ++ot) {
        int o = (w * 2 + ot) * 16 + l15;
        #pragma unroll
        for (int ks = 0; ks < 4; ++ks) {
            const float* wp = W + o * 128 + ks * 32 + lg * 8;
            float4 v0 = *(const float4*)wp;
            float4 v1 = *(const float4*)(wp + 4);
            uint4 pk;
            pk.x = pack2(v0.x, v0.y); pk.y = pack2(v0.z, v0.w);
            pk.z = pack2(v1.x, v1.y); pk.w = pack2(v1.z, v1.w);
            af[ot][ks] = *(bf16x8*)&pk;
        }
    }

    f32x4 acc[2][4];
    #pragma unroll
    for (int ot = 0; ot < 2; ++ot)
        #pragma unroll
        for (int dg = 0; dg < 4; ++dg) acc[ot][dg] = fzero;

    #pragma unroll
    for (int dg = 0; dg < 4; ++dg) {
        int d = dg * 16 + l15;
        #pragma unroll
        for (int ks = 0; ks < 4; ++ks) {
            bf16x8 bx = *(const bf16x8*)&xt[d * 128 + ((ks * 32 + lg * 8) ^ ((d & 7) << 3))];
            acc[0][dg] = __builtin_amdgcn_mfma_f32_16x16x32_bf16(af[0][ks], bx, acc[0][dg], 0, 0, 0);
            acc[1][dg] = __builtin_amdgcn_mfma_f32_16x16x32_bf16(af[1][ks], bx, acc[1][dg], 0, 0, 0);
        }
    }

    if (z < 2) {
        // fused BN partial stats (per-channel sum/sumsq over this block's 64 d)
        float* ps  = part + (size_t)(z * 2 + 0) * 65536;
        float* pss = part + (size_t)(z * 2 + 1) * 65536;
        #pragma unroll
        for (int ot = 0; ot < 2; ++ot) {
            #pragma unroll
            for (int r = 0; r < 4; ++r) {
                float a0 = acc[ot][0][r], a1 = acc[ot][1][r];
                float a2 = acc[ot][2][r], a3 = acc[ot][3][r];
                float s = (a0 + a1) + (a2 + a3);
                float q = (a0 * a0 + a1 * a1) + (a2 * a2 + a3 * a3);
                s += __shfl_xor(s, 1); s += __shfl_xor(s, 2);
                s += __shfl_xor(s, 4); s += __shfl_xor(s, 8);
                q += __shfl_xor(q, 1); q += __shfl_xor(q, 2);
                q += __shfl_xor(q, 4); q += __shfl_xor(q, 8);
                if (l15 == 0) {
                    int o = (w * 2 + ot) * 16 + lg * 4 + r;
                    ps [o * 512 + bid] = s;
                    pss[o * 512 + bid] = q;
                }
            }
        }
        // stage [d][c] in LDS (swizzled), then coalesced uint4 stores
        #pragma unroll
        for (int ot = 0; ot < 2; ++ot) {
            #pragma unroll
            for (int dg = 0; dg < 4; ++dg) {
                int row = dg * 16 + l15;
                int col = (w * 2 + ot) * 16 + lg * 4;
                uint2 p;
                p.x = pack2(acc[ot][dg][0], acc[ot][dg][1]);
                p.y = pack2(acc[ot][dg][2], acc[ot][dg][3]);
                *(uint2*)&fgT[row * 128 + (col ^ ((row & 7) << 3))] = p;
            }
        }
        __syncthreads();
        short* Y = z ? gt : ft;
        #pragma unroll
        for (int k = 0; k < 4; ++k) {
            int u = t + k * 256;
            int row = u >> 4, c8 = (u & 15) * 8;
            uint4 v = *(const uint4*)&fgT[row * 128 + (c8 ^ ((row & 7) << 3))];
            *(uint4*)&Y[((size_t)b * D_LEN + dblk + row) * C_CH + c8] = v;
        }
    } else {
        // h: +bias, transpose through LDS, coalesced uint4 stores
        #pragma unroll
        for (int ot = 0; ot < 2; ++ot) {
            #pragma unroll
            for (int r = 0; r < 4; ++r) {
                int o = (w * 2 + ot) * 16 + lg * 4 + r;
                float bo = bh[o];
                #pragma unroll
                for (int dg = 0; dg < 4; ++dg)
                    hT[o * 72 + dg * 16 + l15] = (short)f2bf(acc[ot][dg][r] + bo);
            }
        }
        __syncthreads();
        #pragma unroll
        for (int k = 0; k < 4; ++k) {
            int idx = t + k * 256;
            int row = idx >> 3, q8 = (idx & 7) * 8;
            uint4 v = *(const uint4*)&hT[row * 72 + q8];
            *(uint4*)&hh[((size_t)(b * C_CH) + row) * D_LEN + dblk + q8] = v;
        }
    }
}

// ---------------------------------------------------------------------------
// BN stats stage 2. SQ folds 128^(-1/4) (QK scale) and sqrt(log2 e)
// (exp->exp2 conversion) into both coefficients.
// ---------------------------------------------------------------------------
__global__ __launch_bounds__(256) void bnstat2_kernel(
    const float* __restrict__ part,
    const float* __restrict__ gf, const float* __restrict__ btf,
    const float* __restrict__ gg, const float* __restrict__ btg,
    float* __restrict__ coefA, float* __restrict__ coefB)
{
    const int ch = blockIdx.x;
    const int which = ch >> 7, c = ch & 127;
    const int t = threadIdx.x;
    const float* ps  = part + (size_t)(which * 2 + 0) * 65536 + c * 512;
    const float* pss = part + (size_t)(which * 2 + 1) * 65536 + c * 512;
    float2 sv = *(const float2*)&ps[t * 2];
    float2 qv = *(const float2*)&pss[t * 2];
    float s = sv.x + sv.y, q = qv.x + qv.y;
    #pragma unroll
    for (int off = 32; off > 0; off >>= 1) {
        s += __shfl_xor(s, off);
        q += __shfl_xor(q, off);
    }
    __shared__ float rs[4], rq[4];
    if ((t & 63) == 0) { rs[t >> 6] = s; rq[t >> 6] = q; }
    __syncthreads();
    if (t == 0) {
        s = rs[0] + rs[1] + rs[2] + rs[3];
        q = rq[0] + rq[1] + rq[2] + rq[3];
        const float inv = 1.0f / 32768.0f;
        const float SQ  = 0.29730177875068026f * 1.2011224087864498f; // 128^-.25 * sqrt(log2e)
        float m    = s * inv;
        float var  = q * inv - m * m;
        float rstd = rsqrtf(var + 1e-5f);
        float gma  = which ? gg[c] : gf[c];
        float bta  = which ? btg[c] : btf[c];
        float a    = gma * rstd;
        coefA[ch] = a * SQ;
        coefB[ch] = (bta - m * a) * SQ;
    }
}

// ---------------------------------------------------------------------------
// BN+ReLU apply in place on ft/gt (scales pre-folded).
// ---------------------------------------------------------------------------
__global__ __launch_bounds__(256) void bnapply_kernel(
    short* __restrict__ ft, short* __restrict__ gt,
    const float* __restrict__ coefA, const float* __restrict__ coefB)
{
    const int gid   = blockIdx.x * 256 + threadIdx.x;
    const int which = gid >> 19;
    const int idx   = gid & 524287;
    short* Y = which ? gt : ft;
    const int c0 = (idx & 15) * 8;
    const float4 a0 = *(const float4*)&coefA[which * 128 + c0];
    const float4 a1 = *(const float4*)&coefA[which * 128 + c0 + 4];
    const float4 b0 = *(const float4*)&coefB[which * 128 + c0];
    const float4 b1 = *(const float4*)&coefB[which * 128 + c0 + 4];
    uint4 v = *(const uint4*)&Y[(size_t)idx * 8];
    uint4 o;
    o.x = pack2(fmaxf(fmaf(a0.x, bfl(v.x), b0.x), 0.f),
                fmaxf(fmaf(a0.y, bfh(v.x), b0.y), 0.f));
    o.y = pack2(fmaxf(fmaf(a0.z, bfl(v.y), b0.z), 0.f),
                fmaxf(fmaf(a0.w, bfh(v.y), b0.w), 0.f));
    o.z = pack2(fmaxf(fmaf(a1.x, bfl(v.z), b1.x), 0.f),
                fmaxf(fmaf(a1.y, bfh(v.z), b1.y), 0.f));
    o.w = pack2(fmaxf(fmaf(a1.z, bfl(v.w), b1.z), 0.f),
                fmaxf(fmaf(a1.w, bfh(v.w), b1.w), 0.f));
    *(uint4*)&Y[(size_t)idx * 8] = o;
}

// ---------------------------------------------------------------------------
// Kernel C: flash attention. grid 512, XCD swizzle. Double-buffered
// global_load_lds staging (pre-swizzled source, linear LDS dest), counted
// vmcnt, raw barriers. Wave-local P, fixed-shift softmax in exp2 domain
// (log2e pre-folded into f/g via SQ).
// ---------------------------------------------------------------------------
#define M_SHIFT2 8.656170245333781f   // 6 * log2(e)

__global__ __launch_bounds__(256) void flashattn_kernel(
    const short* __restrict__ ft, const short* __restrict__ gt,
    const short* __restrict__ hh, short* __restrict__ z2t)
{
    __shared__ __align__(16) short g_lds[2][64 * 128];
    __shared__ __align__(16) short h_lds[2][128 * 64];
    __shared__ __align__(16) short p_lds[64 * 64];

    const int t    = threadIdx.x;
    const int lane = t & 63;
    const int w    = t >> 6;
    const int l15  = lane & 15, lg = lane >> 4;

    const int L  = blockIdx.x;
    const int r_ = L >> 3;
    const int b    = (L & 7) * 2 + (r_ >> 5);
    const int dblk = (r_ & 31) * 64;

    const size_t gbase = (size_t)b * D_LEN * C_CH;      // ft/gt [b][d|e][c]
    const size_t hbase = (size_t)(b * C_CH) * D_LEN;    // hh [b][c][e]

    const int g_row  = t >> 4;            // 0..15 (+16/chunk)
    const int g_colS = (t & 15) * 8;      // shorts
    const int h_row  = t >> 3;            // 0..31 (+32/chunk)
    const int h_colS = (t & 7) * 8;

    auto stage_issue = [&](int e0, int bb) {
        #pragma unroll
        for (int k = 0; k < 4; ++k) {
            int row = g_row + k * 16;
            const short* src = gt + gbase + (size_t)(e0 + row) * C_CH
                             + (g_colS ^ ((row & 7) << 3));
            gl_lds16(src, &g_lds[bb][k * 2048 + t * 8]);
        }
        #pragma unroll
        for (int k = 0; k < 4; ++k) {
            int row = h_row + k * 32;
            const short* src = hh + hbase + (size_t)row * D_LEN + e0
                             + (h_colS ^ ((row & 7) << 3));
            gl_lds16(src, &h_lds[bb][k * 2048 + t * 8]);
        }
    };

    // stage f into g_lds[0] (regular), hoist loop-invariant B-frags
    {
        const size_t fb = gbase + (size_t)dblk * C_CH;
        #pragma unroll
        for (int k = 0; k < 4; ++k) {
            int row = g_row + k * 16;
            uint4 v = *(const uint4*)(ft + fb + (size_t)row * C_CH + g_colS);
            *(uint4*)&g_lds[0][(row * 128 + g_colS) ^ ((row & 7) << 3)] = v;
        }
    }
    __syncthreads();
    const int drow = w * 16 + l15;
    bf16x8 bfrag[4];
    #pragma unroll
    for (int ks = 0; ks < 4; ++ks)
        bfrag[ks] = *(const bf16x8*)&g_lds[0][(drow * 128 + ks * 32 + lg * 8) ^ ((drow & 7) << 3)];
    __syncthreads();   // all waves done reading f

    stage_issue(0, 0);
    stage_issue(64, 1);

    float l_run = 0.f;
    const f32x4 fzero = {0.f, 0.f, 0.f, 0.f};
    f32x4 acc[8];
    #pragma unroll
    for (int n = 0; n < 8; ++n) acc[n] = fzero;

    for (int i = 0; i < 32; ++i) {
        const int cur = i & 1;
        const short* gl = g_lds[cur];
        const short* hl = h_lds[cur];

        if (i < 31) asm volatile("s_waitcnt vmcnt(8)" ::: "memory");
        else        asm volatile("s_waitcnt vmcnt(0)" ::: "memory");
        __builtin_amdgcn_s_barrier();

        // QK
        f32x4 st[4];
        #pragma unroll
        for (int m = 0; m < 4; ++m) st[m] = fzero;
        __builtin_amdgcn_s_setprio(1);
        #pragma unroll
        for (int m = 0; m < 4; ++m) {
            int erow = m * 16 + l15;
            #pragma unroll
            for (int ks = 0; ks < 4; ++ks) {
                bf16x8 ag = *(const bf16x8*)&gl[(erow * 128 + ks * 32 + lg * 8) ^ ((erow & 7) << 3)];
                st[m] = __builtin_amdgcn_mfma_f32_16x16x32_bf16(ag, bfrag[ks], st[m], 0, 0, 0);
            }
        }
        __builtin_amdgcn_s_setprio(0);

        // fixed-shift softmax in exp2 domain (wave-local rows)
        float psum = 0.f;
        #pragma unroll
        for (int m = 0; m < 4; ++m) {
            float p0 = exp2f(st[m][0] - M_SHIFT2);
            float p1 = exp2f(st[m][1] - M_SHIFT2);
            float p2 = exp2f(st[m][2] - M_SHIFT2);
            float p3 = exp2f(st[m][3] - M_SHIFT2);
            psum += (p0 + p1) + (p2 + p3);
            uint2 pv;
            pv.x = pack2(p0, p1);
            pv.y = pack2(p2, p3);
            *(uint2*)&p_lds[(drow * 64 + m * 16 + lg * 4) ^ ((drow & 7) << 3)] = pv;
        }
        psum += __shfl_xor(psum, 16);
        psum += __shfl_xor(psum, 32);
        l_run += psum;

        asm volatile("s_waitcnt lgkmcnt(0)" ::: "memory");
        __builtin_amdgcn_sched_barrier(0);

        // PV
        bf16x8 pa[2];
        #pragma unroll
        for (int ks = 0; ks < 2; ++ks)
            pa[ks] = *(const bf16x8*)&p_lds[(drow * 64 + ks * 32 + lg * 8) ^ ((drow & 7) << 3)];
        __builtin_amdgcn_s_setprio(1);
        #pragma unroll
        for (int n = 0; n < 8; ++n) {
            int crow = n * 16 + l15;
            #pragma unroll
            for (int ks = 0; ks < 2; ++ks) {
                bf16x8 hb_ = *(const bf16x8*)&hl[(crow * 64 + ks * 32 + lg * 8) ^ ((crow & 7) << 3)];
                acc[n] = __builtin_amdgcn_mfma_f32_16x16x32_bf16(pa[ks], hb_, acc[n], 0, 0, 0);
            }
        }
        __builtin_amdgcn_s_setprio(0);

        __builtin_amdgcn_s_barrier();
        if (i + 2 < 32) stage_issue((i + 2) * 64, cur);
    }

    // epilogue: O through LDS -> coalesced uint4 stores
    float rl[4];
    #pragma unroll
    for (int r = 0; r < 4; ++r)
        rl[r] = 1.0f / __shfl(l_run, lg * 4 + r);

    __syncthreads();
    #pragma unroll
    for (int n = 0; n < 8; ++n) {
        int col = n * 16 + l15;
        #pragma unroll
        for (int r = 0; r < 4; ++r) {
            int row = w * 16 + lg * 4 + r;
            g_lds[0][row * 128 + (col ^ ((row & 7) << 3))] = (short)f2bf(acc[n][r] * rl[r]);
        }
    }
    __syncthreads();
    {
        const size_t zb = ((size_t)b * D_LEN + dblk) * C_CH;
        #pragma unroll
        for (int k = 0; k < 4; ++k) {
            int u = t + k * 256;
            int row = u >> 4, c8 = (u & 15) * 8;
            uint4 v = *(const uint4*)&g_lds[0][row * 128 + (c8 ^ ((row & 7) << 3))];
            *(uint4*)&z2t[zb + (size_t)row * C_CH + c8] = v;
        }
    }
}

// ---------------------------------------------------------------------------
// Kernel D: out = Wv z2 + bv + x via MFMA. grid (32,16).
// ---------------------------------------------------------------------------
__global__ __launch_bounds__(256) void convout_kernel(
    const short* __restrict__ z2t, const float* __restrict__ Wv,
    const float* __restrict__ bv, const float* __restrict__ x,
    float* __restrict__ out)
{
    __shared__ __align__(16) short zt[64 * 128];

    const int t    = threadIdx.x;
    const int lane = t & 63;
    const int w    = t >> 6;
    const int l15  = lane & 15, lg = lane >> 4;
    const int dblk = blockIdx.x * 64;
    const int b    = blockIdx.y;
    const size_t base = (size_t)b * C_CH * D_LEN;

    {
        const size_t zb = ((size_t)b * D_LEN + dblk) * C_CH;
        #pragma unroll
        for (int k = 0; k < 4; ++k) {
            int u = t + k * 256;
            int row = u >> 4, cq = (u & 15) * 8;
            uint4 v = *(const uint4*)(z2t + zb + (size_t)row * C_CH + cq);
            *(uint4*)&zt[(row * 128 + cq) ^ ((row & 7) << 3)] = v;
        }
    }

    bf16x8 af[2][4];
    #pragma unroll
    for (int ot = 0; ot < 2; ++ot) {
        int o = (w * 2 + ot) * 16 + l15;
        #pragma unroll
        for (int ks = 0; ks < 4; ++ks) {
            const float* wp = Wv + o * 128 + ks * 32 + lg * 8;
            float4 v0 = *(const float4*)wp;
            float4 v1 = *(const float4*)(wp + 4);
            uint4 pk;
            pk.x = pack2(v0.x, v0.y); pk.y = pack2(v0.z, v0.w);
            pk.z = pack2(v1.x, v1.y); pk.w = pack2(v1.z, v1.w);
            af[ot][ks] = *(bf16x8*)&pk;
        }
    }
    __syncthreads();

    const f32x4 fzero = {0.f, 0.f, 0.f, 0.f};
    f32x4 acc[2][4];
    #pragma unroll
    for (int ot = 0; ot < 2; ++ot)
        #pragma unroll
        for (int dg = 0; dg < 4; ++dg) acc[ot][dg] = fzero;

    #pragma unroll
    for (int dg = 0; dg < 4; ++dg) {
        int d = dg * 16 + l15;
        #pragma unroll
        for (int ks = 0; ks < 4; ++ks) {
            bf16x8 bx = *(const bf16x8*)&zt[d * 128 + ((ks * 32 + lg * 8) ^ ((d & 7) << 3))];
            acc[0][dg] = __builtin_amdgcn_mfma_f32_16x16x32_bf16(af[0][ks], bx, acc[0][dg], 0, 0, 0);
            acc[1][dg] = __builtin_amdgcn_mfma_f32_16x16x32_bf16(af[1][ks], bx, acc[1][dg], 0, 0, 0);
        }
    }

    #pragma unroll
    for (int ot = 0; ot < 2; ++ot) {
        #pragma unroll
        for (int r = 0; r < 4; ++r) {
            int o = (w * 2 + ot) * 16 + lg * 4 + r;
            float bo = bv[o];
            const float* xr  = x   + base + (size_t)o * D_LEN + dblk;
            float*      orow = out + base + (size_t)o * D_LEN + dblk;
            #pragma unroll
            for (int dg = 0; dg < 4; ++dg) {
                int d = dg * 16 + l15;
                orow[d] = acc[ot][dg][r] + bo + xr[d];
            }
        }
    }
}

// ---------------------------------------------------------------------------
extern "C" void kernel_launch(void* const* d_in, const int* in_sizes, int n_in,
                              void* d_out, int out_size, void* d_ws, size_t ws_size,
                              hipStream_t stream)
{
    const float* x   = (const float*)d_in[0];
    const float* Wf  = (const float*)d_in[1];
    const float* gf  = (const float*)d_in[3];
    const float* btf = (const float*)d_in[4];
    const float* Wg  = (const float*)d_in[5];
    const float* gg  = (const float*)d_in[7];
    const float* btg = (const float*)d_in[8];
    const float* Wh  = (const float*)d_in[9];
    const float* bh  = (const float*)d_in[10];
    const float* Wv  = (const float*)d_in[11];
    const float* bv  = (const float*)d_in[12];
    float* out = (float*)d_out;

    const size_t elems = (size_t)NB * C_CH * D_LEN;   // 4,194,304
    short* ft    = (short*)d_ws;
    short* gt    = ft + elems;
    short* hh    = gt + elems;
    short* z2t   = hh + elems;
    float* part  = (float*)(z2t + elems);     // 4 * 65536 floats
    float* coefA = part + 262144;
    float* coefB = coefA + 256;

    conv3_kernel<<<dim3(32, NB, 3), 256, 0, stream>>>(
        x, Wf, Wg, Wh, bh, ft, gt, hh, part);
    bnstat2_kernel<<<dim3(256), 256, 0, stream>>>(
        part, gf, btf, gg, btg, coefA, coefB);
    bnapply_kernel<<<dim3(4096), 256, 0, stream>>>(ft, gt, coefA, coefB);
    flashattn_kernel<<<dim3(512), 256, 0, stream>>>(ft, gt, hh, z2t);
    convout_kernel<<<dim3(32, NB), 256, 0, stream>>>(z2t, Wv, bv, x, out);
}

// Round 9
// 177.720 us; speedup vs baseline: 1.0491x; 1.0491x over previous
//
#include <hip/hip_runtime.h>
#include <math.h>

#define D_LEN 2048
#define C_CH  128
#define NB    16

typedef __attribute__((ext_vector_type(8))) short bf16x8;
typedef __attribute__((ext_vector_type(4))) float f32x4;

__device__ __forceinline__ unsigned int f2bf(float x){
    unsigned int u = __float_as_uint(x);
    return (u + 0x7fffu + ((u >> 16) & 1u)) >> 16;     // RNE
}
__device__ __forceinline__ unsigned int pack2(float a, float b){
    return f2bf(a) | (f2bf(b) << 16);
}
__device__ __forceinline__ float bfl(unsigned int u){ return __uint_as_float(u << 16); }
__device__ __forceinline__ float bfh(unsigned int u){ return __uint_as_float(u & 0xffff0000u); }

// native 2^x (guaranteed v_exp_f32, no library range-check path)
__device__ __forceinline__ float exp2v(float x){
    float r; asm("v_exp_f32 %0, %1" : "=v"(r) : "v"(x)); return r;
}
// packed fp32x2 -> bf16x2 RNE in one instruction
__device__ __forceinline__ unsigned int cvtpk(float a, float b){
    unsigned int r; asm("v_cvt_pk_bf16_f32 %0, %1, %2" : "=v"(r) : "v"(a), "v"(b)); return r;
}

// async global->LDS, 16B per lane; LDS dest = wave-uniform base + lane*16
__device__ __forceinline__ void gl_lds16(const void* g, void* l) {
    __builtin_amdgcn_global_load_lds(
        (const __attribute__((address_space(1))) unsigned int*)g,
        (__attribute__((address_space(3))) unsigned int*)l, 16, 0, 0);
}

// ---------------------------------------------------------------------------
// Kernel A: 1x1 convs via MFMA, one conv per blockIdx.z. grid (32,16,3).
// z<2 (f,g): raw conv bf16 [b][d][c] + fused BN partial stats.
// z=2 (h): conv+bh, bf16 [b][c][d] via LDS transpose.
// ---------------------------------------------------------------------------
__global__ __launch_bounds__(256) void conv3_kernel(
    const float* __restrict__ x,
    const float* __restrict__ Wf, const float* __restrict__ Wg,
    const float* __restrict__ Wh, const float* __restrict__ bh,
    short* __restrict__ ft, short* __restrict__ gt, short* __restrict__ hh,
    float* __restrict__ part)
{
    __shared__ __align__(16) char smem[34816 + 16384];
    float* xs  = (float*)smem;              // [128][68] fp32 (phase 1)
    short* fgT = (short*)smem;              // [64][128] bf16 staging (reuse)
    short* hT  = (short*)smem;              // [128][72] bf16 (h epilogue)
    short* xt  = (short*)(smem + 34816);    // [64][128] bf16 swizzled

    const int t    = threadIdx.x;
    const int lane = t & 63;
    const int w    = t >> 6;
    const int l15  = lane & 15, lg = lane >> 4;
    const int dblk = blockIdx.x * 64;
    const int b    = blockIdx.y;
    const int z    = blockIdx.z;
    const int bid  = b * 32 + blockIdx.x;   // 0..511
    const size_t xbase = (size_t)b * C_CH * D_LEN;
    const float* W = (z == 0) ? Wf : (z == 1) ? Wg : Wh;

    #pragma unroll
    for (int k = 0; k < 8; ++k) {
        int u = t + k * 256;
        int c = u >> 4, d4 = (u & 15) * 4;
        float4 v = *(const float4*)(x + xbase + (size_t)c * D_LEN + dblk + d4);
        *(float4*)&xs[c * 68 + d4] = v;
    }
    __syncthreads();

    {
        const int d  = t & 63;
        const int cw = t >> 6;
        #pragma unroll
        for (int k = 0; k < 4; ++k) {
            int c0 = (cw + 4 * k) * 8;
            float v[8];
            #pragma unroll
            for (int j = 0; j < 8; ++j) v[j] = xs[(c0 + j) * 68 + d];
            uint4 o;
            o.x = pack2(v[0], v[1]); o.y = pack2(v[2], v[3]);
            o.z = pack2(v[4], v[5]); o.w = pack2(v[6], v[7]);
            *(uint4*)&xt[d * 128 + (c0 ^ ((d & 7) << 3))] = o;
        }
    }
    __syncthreads();

    const f32x4 fzero = {0.f, 0.f, 0.f, 0.f};

    bf16x8 af[2][4];
    #pragma unroll
    for (int ot = 0; ot < 2; ++ot) {
        int o = (w * 2 + ot) * 16 + l15;
        #pragma unroll
        for (int ks = 0; ks < 4; ++ks) {
            const float* wp = W + o * 128 + ks * 32 + lg * 8;
            float4 v0 = *(const float4*)wp;
            float4 v1 = *(const float4*)(wp + 4);
            uint4 pk;
            pk.x = pack2(v0.x, v0.y); pk.y = pack2(v0.z, v0.w);
            pk.z = pack2(v1.x, v1.y); pk.w = pack2(v1.z, v1.w);
            af[ot][ks] = *(bf16x8*)&pk;
        }
    }

    f32x4 acc[2][4];
    #pragma unroll
    for (int ot = 0; ot < 2; ++ot)
        #pragma unroll
        for (int dg = 0; dg < 4; ++dg) acc[ot][dg] = fzero;

    #pragma unroll
    for (int dg = 0; dg < 4; ++dg) {
        int d = dg * 16 + l15;
        #pragma unroll
        for (int ks = 0; ks < 4; ++ks) {
            bf16x8 bx = *(const bf16x8*)&xt[d * 128 + ((ks * 32 + lg * 8) ^ ((d & 7) << 3))];
            acc[0][dg] = __builtin_amdgcn_mfma_f32_16x16x32_bf16(af[0][ks], bx, acc[0][dg], 0, 0, 0);
            acc[1][dg] = __builtin_amdgcn_mfma_f32_16x16x32_bf16(af[1][ks], bx, acc[1][dg], 0, 0, 0);
        }
    }

    if (z < 2) {
        float* ps  = part + (size_t)(z * 2 + 0) * 65536;
        float* pss = part + (size_t)(z * 2 + 1) * 65536;
        #pragma unroll
        for (int ot = 0; ot < 2; ++ot) {
            #pragma unroll
            for (int r = 0; r < 4; ++r) {
                float a0 = acc[ot][0][r], a1 = acc[ot][1][r];
                float a2 = acc[ot][2][r], a3 = acc[ot][3][r];
                float s = (a0 + a1) + (a2 + a3);
                float q = (a0 * a0 + a1 * a1) + (a2 * a2 + a3 * a3);
                s += __shfl_xor(s, 1); s += __shfl_xor(s, 2);
                s += __shfl_xor(s, 4); s += __shfl_xor(s, 8);
                q += __shfl_xor(q, 1); q += __shfl_xor(q, 2);
                q += __shfl_xor(q, 4); q += __shfl_xor(q, 8);
                if (l15 == 0) {
                    int o = (w * 2 + ot) * 16 + lg * 4 + r;
                    ps [o * 512 + bid] = s;
                    pss[o * 512 + bid] = q;
                }
            }
        }
        #pragma unroll
        for (int ot = 0; ot < 2; ++ot) {
            #pragma unroll
            for (int dg = 0; dg < 4; ++dg) {
                int row = dg * 16 + l15;
                int col = (w * 2 + ot) * 16 + lg * 4;
                uint2 p;
                p.x = pack2(acc[ot][dg][0], acc[ot][dg][1]);
                p.y = pack2(acc[ot][dg][2], acc[ot][dg][3]);
                *(uint2*)&fgT[row * 128 + (col ^ ((row & 7) << 3))] = p;
            }
        }
        __syncthreads();
        short* Y = z ? gt : ft;
        #pragma unroll
        for (int k = 0; k < 4; ++k) {
            int u = t + k * 256;
            int row = u >> 4, c8 = (u & 15) * 8;
            uint4 v = *(const uint4*)&fgT[row * 128 + (c8 ^ ((row & 7) << 3))];
            *(uint4*)&Y[((size_t)b * D_LEN + dblk + row) * C_CH + c8] = v;
        }
    } else {
        #pragma unroll
        for (int ot = 0; ot < 2; ++ot) {
            #pragma unroll
            for (int r = 0; r < 4; ++r) {
                int o = (w * 2 + ot) * 16 + lg * 4 + r;
                float bo = bh[o];
                #pragma unroll
                for (int dg = 0; dg < 4; ++dg)
                    hT[o * 72 + dg * 16 + l15] = (short)f2bf(acc[ot][dg][r] + bo);
            }
        }
        __syncthreads();
        #pragma unroll
        for (int k = 0; k < 4; ++k) {
            int idx = t + k * 256;
            int row = idx >> 3, q8 = (idx & 7) * 8;
            uint4 v = *(const uint4*)&hT[row * 72 + q8];
            *(uint4*)&hh[((size_t)(b * C_CH) + row) * D_LEN + dblk + q8] = v;
        }
    }
}

// ---------------------------------------------------------------------------
// BN stats stage 2. SQ folds 128^(-1/4) and sqrt(log2 e).
// ---------------------------------------------------------------------------
__global__ __launch_bounds__(256) void bnstat2_kernel(
    const float* __restrict__ part,
    const float* __restrict__ gf, const float* __restrict__ btf,
    const float* __restrict__ gg, const float* __restrict__ btg,
    float* __restrict__ coefA, float* __restrict__ coefB)
{
    const int ch = blockIdx.x;
    const int which = ch >> 7, c = ch & 127;
    const int t = threadIdx.x;
    const float* ps  = part + (size_t)(which * 2 + 0) * 65536 + c * 512;
    const float* pss = part + (size_t)(which * 2 + 1) * 65536 + c * 512;
    float2 sv = *(const float2*)&ps[t * 2];
    float2 qv = *(const float2*)&pss[t * 2];
    float s = sv.x + sv.y, q = qv.x + qv.y;
    #pragma unroll
    for (int off = 32; off > 0; off >>= 1) {
        s += __shfl_xor(s, off);
        q += __shfl_xor(q, off);
    }
    __shared__ float rs[4], rq[4];
    if ((t & 63) == 0) { rs[t >> 6] = s; rq[t >> 6] = q; }
    __syncthreads();
    if (t == 0) {
        s = rs[0] + rs[1] + rs[2] + rs[3];
        q = rq[0] + rq[1] + rq[2] + rq[3];
        const float inv = 1.0f / 32768.0f;
        const float SQ  = 0.29730177875068026f * 1.2011224087864498f; // 128^-.25 * sqrt(log2e)
        float m    = s * inv;
        float var  = q * inv - m * m;
        float rstd = rsqrtf(var + 1e-5f);
        float gma  = which ? gg[c] : gf[c];
        float bta  = which ? btg[c] : btf[c];
        float a    = gma * rstd;
        coefA[ch] = a * SQ;
        coefB[ch] = (bta - m * a) * SQ;
    }
}

// ---------------------------------------------------------------------------
// BN+ReLU apply in place on ft/gt (scales pre-folded).
// ---------------------------------------------------------------------------
__global__ __launch_bounds__(256) void bnapply_kernel(
    short* __restrict__ ft, short* __restrict__ gt,
    const float* __restrict__ coefA, const float* __restrict__ coefB)
{
    const int gid   = blockIdx.x * 256 + threadIdx.x;
    const int which = gid >> 19;
    const int idx   = gid & 524287;
    short* Y = which ? gt : ft;
    const int c0 = (idx & 15) * 8;
    const float4 a0 = *(const float4*)&coefA[which * 128 + c0];
    const float4 a1 = *(const float4*)&coefA[which * 128 + c0 + 4];
    const float4 b0 = *(const float4*)&coefB[which * 128 + c0];
    const float4 b1 = *(const float4*)&coefB[which * 128 + c0 + 4];
    uint4 v = *(const uint4*)&Y[(size_t)idx * 8];
    uint4 o;
    o.x = cvtpk(fmaxf(fmaf(a0.x, bfl(v.x), b0.x), 0.f),
                fmaxf(fmaf(a0.y, bfh(v.x), b0.y), 0.f));
    o.y = cvtpk(fmaxf(fmaf(a0.z, bfl(v.y), b0.z), 0.f),
                fmaxf(fmaf(a0.w, bfh(v.y), b0.w), 0.f));
    o.z = cvtpk(fmaxf(fmaf(a1.x, bfl(v.z), b1.x), 0.f),
                fmaxf(fmaf(a1.y, bfh(v.z), b1.y), 0.f));
    o.w = cvtpk(fmaxf(fmaf(a1.z, bfl(v.w), b1.z), 0.f),
                fmaxf(fmaf(a1.w, bfh(v.w), b1.w), 0.f));
    *(uint4*)&Y[(size_t)idx * 8] = o;
}

// ---------------------------------------------------------------------------
// Kernel C: flash attention + FUSED output conv. grid 512, XCD swizzle.
// Double-buffered global_load_lds, counted vmcnt, wave-local P, softmax
// shift folded into MFMA C-init, native v_exp/v_cvt_pk.
// Epilogue: O->LDS -> MFMA with Wv -> out = Wv*O + bv + x (fp32).
// ---------------------------------------------------------------------------
#define M_SHIFT2 8.656170245333781f   // 6 * log2(e)

__global__ __launch_bounds__(256) void flashattn_kernel(
    const short* __restrict__ ft, const short* __restrict__ gt,
    const short* __restrict__ hh, const float* __restrict__ Wv,
    const float* __restrict__ bv, const float* __restrict__ x,
    float* __restrict__ out)
{
    __shared__ __align__(16) short g_lds[2][64 * 128];
    __shared__ __align__(16) short h_lds[2][128 * 64];
    __shared__ __align__(16) short p_lds[64 * 64];

    const int t    = threadIdx.x;
    const int lane = t & 63;
    const int w    = t >> 6;
    const int l15  = lane & 15, lg = lane >> 4;

    const int L  = blockIdx.x;
    const int r_ = L >> 3;
    const int b    = (L & 7) * 2 + (r_ >> 5);
    const int dblk = (r_ & 31) * 64;

    const size_t gbase = (size_t)b * D_LEN * C_CH;      // ft/gt [b][d|e][c]
    const size_t hbase = (size_t)(b * C_CH) * D_LEN;    // hh [b][c][e]

    const int g_row  = t >> 4;            // 0..15 (+16/chunk)
    const int g_colS = (t & 15) * 8;      // shorts
    const int h_row  = t >> 3;            // 0..31 (+32/chunk)
    const int h_colS = (t & 7) * 8;

    auto stage_issue = [&](int e0, int bb) {
        #pragma unroll
        for (int k = 0; k < 4; ++k) {
            int row = g_row + k * 16;
            const short* src = gt + gbase + (size_t)(e0 + row) * C_CH
                             + (g_colS ^ ((row & 7) << 3));
            gl_lds16(src, &g_lds[bb][k * 2048 + t * 8]);
        }
        #pragma unroll
        for (int k = 0; k < 4; ++k) {
            int row = h_row + k * 32;
            const short* src = hh + hbase + (size_t)row * D_LEN + e0
                             + (h_colS ^ ((row & 7) << 3));
            gl_lds16(src, &h_lds[bb][k * 2048 + t * 8]);
        }
    };

    // stage f into g_lds[0] (regular), hoist loop-invariant B-frags
    {
        const size_t fb = gbase + (size_t)dblk * C_CH;
        #pragma unroll
        for (int k = 0; k < 4; ++k) {
            int row = g_row + k * 16;
            uint4 v = *(const uint4*)(ft + fb + (size_t)row * C_CH + g_colS);
            *(uint4*)&g_lds[0][(row * 128 + g_colS) ^ ((row & 7) << 3)] = v;
        }
    }
    __syncthreads();
    const int drow = w * 16 + l15;
    bf16x8 bfrag[4];
    #pragma unroll
    for (int ks = 0; ks < 4; ++ks)
        bfrag[ks] = *(const bf16x8*)&g_lds[0][(drow * 128 + ks * 32 + lg * 8) ^ ((drow & 7) << 3)];
    __syncthreads();   // all waves done reading f

    stage_issue(0, 0);
    stage_issue(64, 1);

    float l_run = 0.f;
    const f32x4 fzero = {0.f, 0.f, 0.f, 0.f};
    const f32x4 minit = {-M_SHIFT2, -M_SHIFT2, -M_SHIFT2, -M_SHIFT2};
    f32x4 acc[8];
    #pragma unroll
    for (int n = 0; n < 8; ++n) acc[n] = fzero;

    for (int i = 0; i < 32; ++i) {
        const int cur = i & 1;
        const short* gl = g_lds[cur];
        const short* hl = h_lds[cur];

        if (i < 31) asm volatile("s_waitcnt vmcnt(8)" ::: "memory");
        else        asm volatile("s_waitcnt vmcnt(0)" ::: "memory");
        __builtin_amdgcn_s_barrier();

        // QK (softmax shift pre-loaded into accumulator)
        f32x4 st[4];
        #pragma unroll
        for (int m = 0; m < 4; ++m) st[m] = minit;
        __builtin_amdgcn_s_setprio(1);
        #pragma unroll
        for (int m = 0; m < 4; ++m) {
            int erow = m * 16 + l15;
            #pragma unroll
            for (int ks = 0; ks < 4; ++ks) {
                bf16x8 ag = *(const bf16x8*)&gl[(erow * 128 + ks * 32 + lg * 8) ^ ((erow & 7) << 3)];
                st[m] = __builtin_amdgcn_mfma_f32_16x16x32_bf16(ag, bfrag[ks], st[m], 0, 0, 0);
            }
        }
        __builtin_amdgcn_s_setprio(0);

        // softmax: p = 2^(st), wave-local rows
        float psum = 0.f;
        #pragma unroll
        for (int m = 0; m < 4; ++m) {
            float p0 = exp2v(st[m][0]);
            float p1 = exp2v(st[m][1]);
            float p2 = exp2v(st[m][2]);
            float p3 = exp2v(st[m][3]);
            psum += (p0 + p1) + (p2 + p3);
            uint2 pv;
            pv.x = cvtpk(p0, p1);
            pv.y = cvtpk(p2, p3);
            *(uint2*)&p_lds[(drow * 64 + m * 16 + lg * 4) ^ ((drow & 7) << 3)] = pv;
        }
        psum += __shfl_xor(psum, 16);
        psum += __shfl_xor(psum, 32);
        l_run += psum;

        asm volatile("s_waitcnt lgkmcnt(0)" ::: "memory");
        __builtin_amdgcn_sched_barrier(0);

        // PV
        bf16x8 pa[2];
        #pragma unroll
        for (int ks = 0; ks < 2; ++ks)
            pa[ks] = *(const bf16x8*)&p_lds[(drow * 64 + ks * 32 + lg * 8) ^ ((drow & 7) << 3)];
        __builtin_amdgcn_s_setprio(1);
        #pragma unroll
        for (int n = 0; n < 8; ++n) {
            int crow = n * 16 + l15;
            #pragma unroll
            for (int ks = 0; ks < 2; ++ks) {
                bf16x8 hb_ = *(const bf16x8*)&hl[(crow * 64 + ks * 32 + lg * 8) ^ ((crow & 7) << 3)];
                acc[n] = __builtin_amdgcn_mfma_f32_16x16x32_bf16(pa[ks], hb_, acc[n], 0, 0, 0);
            }
        }
        __builtin_amdgcn_s_setprio(0);

        __builtin_amdgcn_s_barrier();
        if (i + 2 < 32) stage_issue((i + 2) * 64, cur);
    }

    // ---- fused output conv epilogue ----
    float rl[4];
    #pragma unroll
    for (int r = 0; r < 4; ++r)
        rl[r] = 1.0f / __shfl(l_run, lg * 4 + r);

    short* gl0 = &g_lds[0][0];
    __syncthreads();   // done with all loop LDS reads; reuse g_lds[0] for O
    #pragma unroll
    for (int n = 0; n < 8; ++n) {
        int col = n * 16 + l15;
        #pragma unroll
        for (int r = 0; r < 4; ++r) {
            int row = w * 16 + lg * 4 + r;
            gl0[row * 128 + (col ^ ((row & 7) << 3))] = (short)f2bf(acc[n][r] * rl[r]);
        }
    }

    // Wv fragments (global fp32, L2-hot) — overlap with LDS O-writes
    bf16x8 af[2][4];
    #pragma unroll
    for (int ot = 0; ot < 2; ++ot) {
        int o = (w * 2 + ot) * 16 + l15;
        #pragma unroll
        for (int ks = 0; ks < 4; ++ks) {
            const float* wp = Wv + o * 128 + ks * 32 + lg * 8;
            float4 v0 = *(const float4*)wp;
            float4 v1 = *(const float4*)(wp + 4);
            uint4 pk;
            pk.x = pack2(v0.x, v0.y); pk.y = pack2(v0.z, v0.w);
            pk.z = pack2(v1.x, v1.y); pk.w = pack2(v1.z, v1.w);
            af[ot][ks] = *(bf16x8*)&pk;
        }
    }
    __syncthreads();

    f32x4 acc2[2][4];
    #pragma unroll
    for (int ot = 0; ot < 2; ++ot)
        #pragma unroll
        for (int dg = 0; dg < 4; ++dg) acc2[ot][dg] = fzero;

    #pragma unroll
    for (int dg = 0; dg < 4; ++dg) {
        int d = dg * 16 + l15;
        #pragma unroll
        for (int ks = 0; ks < 4; ++ks) {
            bf16x8 bx = *(const bf16x8*)&gl0[d * 128 + ((ks * 32 + lg * 8) ^ ((d & 7) << 3))];
            acc2[0][dg] = __builtin_amdgcn_mfma_f32_16x16x32_bf16(af[0][ks], bx, acc2[0][dg], 0, 0, 0);
            acc2[1][dg] = __builtin_amdgcn_mfma_f32_16x16x32_bf16(af[1][ks], bx, acc2[1][dg], 0, 0, 0);
        }
    }

    const size_t base = (size_t)b * C_CH * D_LEN;
    #pragma unroll
    for (int ot = 0; ot < 2; ++ot) {
        #pragma unroll
        for (int r = 0; r < 4; ++r) {
            int o = (w * 2 + ot) * 16 + lg * 4 + r;
            float bo = bv[o];
            const float* xr  = x   + base + (size_t)o * D_LEN + dblk;
            float*      orow = out + base + (size_t)o * D_LEN + dblk;
            #pragma unroll
            for (int dg = 0; dg < 4; ++dg) {
                int d = dg * 16 + l15;
                orow[d] = acc2[ot][dg][r] + bo + xr[d];
            }
        }
    }
}

// ---------------------------------------------------------------------------
extern "C" void kernel_launch(void* const* d_in, const int* in_sizes, int n_in,
                              void* d_out, int out_size, void* d_ws, size_t ws_size,
                              hipStream_t stream)
{
    const float* x   = (const float*)d_in[0];
    const float* Wf  = (const float*)d_in[1];
    const float* gf  = (const float*)d_in[3];
    const float* btf = (const float*)d_in[4];
    const float* Wg  = (const float*)d_in[5];
    const float* gg  = (const float*)d_in[7];
    const float* btg = (const float*)d_in[8];
    const float* Wh  = (const float*)d_in[9];
    const float* bh  = (const float*)d_in[10];
    const float* Wv  = (const float*)d_in[11];
    const float* bv  = (const float*)d_in[12];
    float* out = (float*)d_out;

    const size_t elems = (size_t)NB * C_CH * D_LEN;   // 4,194,304
    short* ft    = (short*)d_ws;
    short* gt    = ft + elems;
    short* hh    = gt + elems;
    float* part  = (float*)(hh + elems);      // 4 * 65536 floats
    float* coefA = part + 262144;
    float* coefB = coefA + 256;

    conv3_kernel<<<dim3(32, NB, 3), 256, 0, stream>>>(
        x, Wf, Wg, Wh, bh, ft, gt, hh, part);
    bnstat2_kernel<<<dim3(256), 256, 0, stream>>>(
        part, gf, btf, gg, btg, coefA, coefB);
    bnapply_kernel<<<dim3(4096), 256, 0, stream>>>(ft, gt, coefA, coefB);
    flashattn_kernel<<<dim3(512), 256, 0, stream>>>(
        ft, gt, hh, Wv, bv, x, out);
}